// Round 4
// baseline (110.705 us; speedup 1.0000x reference)
//
#include <hip/hip_runtime.h>

// Batched 3x3 expm(T) @ x, T = sum_m c[b,m]*psi[m], Cayley-Hamilton reduced
// Taylor (order 10, scaling s=2), exp(T)x = (E)^4 x via 4 matvecs.
// FOUR batches per thread: the serial chain (invariants -> 10-step scalar
// recurrence -> matvecs) is latency-bound at 1 batch/thread; 4 independent
// chains interleave in the scheduler. All global I/O is exact float4:
// x: 3x dwordx4, c: 6x dwordx4, out: 3x dwordx4 per thread.
// B = 2097152 is divisible by 4 (asserted by layout).
__global__ __launch_bounds__(256) void expm_kernel(
    const float4* __restrict__ x4,
    const float4* __restrict__ c4,
    const float* __restrict__ psi,
    float4* __restrict__ out4,
    int Tn)  // Tn = B/4
{
    const int t = blockIdx.x * blockDim.x + threadIdx.x;
    if (t >= Tn) return;

    // ---- load 4 batches of x (12 floats) and c (24 floats), vectorized ----
    float xf[12];
    {
        const float4 a = x4[(size_t)t * 3 + 0];
        const float4 b = x4[(size_t)t * 3 + 1];
        const float4 d = x4[(size_t)t * 3 + 2];
        xf[0] = a.x; xf[1] = a.y; xf[2]  = a.z; xf[3]  = a.w;
        xf[4] = b.x; xf[5] = b.y; xf[6]  = b.z; xf[7]  = b.w;
        xf[8] = d.x; xf[9] = d.y; xf[10] = d.z; xf[11] = d.w;
    }
    float cf[24];
#pragma unroll
    for (int q = 0; q < 6; ++q) {
        const float4 v = c4[(size_t)t * 6 + q];
        cf[q * 4 + 0] = v.x; cf[q * 4 + 1] = v.y;
        cf[q * 4 + 2] = v.z; cf[q * 4 + 3] = v.w;
    }

    float of[12];

#pragma unroll
    for (int u = 0; u < 4; ++u) {
        // ---- A = sum_m (c[m]/4) * psi[m]  (psi uniform -> scalarized) ----
        const float cm[6] = {cf[u * 6 + 0] * 0.25f, cf[u * 6 + 1] * 0.25f,
                             cf[u * 6 + 2] * 0.25f, cf[u * 6 + 3] * 0.25f,
                             cf[u * 6 + 4] * 0.25f, cf[u * 6 + 5] * 0.25f};
        float A[9];
#pragma unroll
        for (int j = 0; j < 9; ++j) {
            float s = cm[0] * psi[0 * 9 + j];
#pragma unroll
            for (int m = 1; m < 6; ++m) s = fmaf(cm[m], psi[m * 9 + j], s);
            A[j] = s;
        }

        // ---- char-poly: lam^3 = c2v lam^2 + c1v lam + c0v ----
        const float tr  = A[0] + A[4] + A[8];
        const float m01 = fmaf(A[0], A[4], -A[1] * A[3]);
        const float m02 = fmaf(A[0], A[8], -A[2] * A[6]);
        const float m12 = fmaf(A[4], A[8], -A[5] * A[7]);
        const float msum = m01 + m02 + m12;
        const float M10 = fmaf(A[3], A[8], -A[5] * A[6]);
        const float M20 = fmaf(A[3], A[7], -A[4] * A[6]);
        const float det = fmaf(A[0], m12, fmaf(-A[1], M10, A[2] * M20));
        const float c2v = tr, c1v = -msum, c0v = det;

        // ---- reduced Taylor, order 10: exp(A) ~ a0 I + a1 A + a2 A^2 ----
        float p0 = 0.0f, p1 = 0.0f, p2 = 1.0f;
        float a0 = 1.0f, a1 = 1.0f, a2 = 0.5f;
        const float invfact[11] = {0, 0, 0,
            1.6666667e-1f,  // 1/3!
            4.1666667e-2f,  // 1/4!
            8.3333333e-3f,  // 1/5!
            1.3888889e-3f,  // 1/6!
            1.9841270e-4f,  // 1/7!
            2.4801587e-5f,  // 1/8!
            2.7557319e-6f,  // 1/9!
            2.7557319e-7f}; // 1/10!
#pragma unroll
        for (int k = 3; k <= 10; ++k) {
            const float t0 = c0v * p2;
            const float t1 = fmaf(c1v, p2, p0);
            const float t2 = fmaf(c2v, p2, p1);
            p0 = t0; p1 = t1; p2 = t2;
            const float f = invfact[k];  // constant after unroll
            a0 = fmaf(p0, f, a0);
            a1 = fmaf(p1, f, a1);
            a2 = fmaf(p2, f, a2);
        }

        // ---- E = a0 I + a1 A + a2 A^2 ----
        float E[9];
#pragma unroll
        for (int i = 0; i < 3; ++i) {
#pragma unroll
            for (int j = 0; j < 3; ++j) {
                float v = A[i * 3 + 0] * A[0 * 3 + j];
                v = fmaf(A[i * 3 + 1], A[1 * 3 + j], v);
                v = fmaf(A[i * 3 + 2], A[2 * 3 + j], v);
                E[i * 3 + j] = fmaf(a2, v, a1 * A[i * 3 + j]);
            }
        }
        E[0] += a0; E[4] += a0; E[8] += a0;

        // ---- y = E^4 x  (E = exp(T/4)) ----
        float y0 = xf[u * 3 + 0], y1 = xf[u * 3 + 1], y2 = xf[u * 3 + 2];
#pragma unroll
        for (int r = 0; r < 4; ++r) {
            const float t0 = fmaf(E[0], y0, fmaf(E[1], y1, E[2] * y2));
            const float t1 = fmaf(E[3], y0, fmaf(E[4], y1, E[5] * y2));
            const float t2 = fmaf(E[6], y0, fmaf(E[7], y1, E[8] * y2));
            y0 = t0; y1 = t1; y2 = t2;
        }
        of[u * 3 + 0] = y0; of[u * 3 + 1] = y1; of[u * 3 + 2] = y2;
    }

    // ---- store 4 batches of out (12 floats), vectorized ----
    float4 s0, s1, s2;
    s0.x = of[0]; s0.y = of[1]; s0.z = of[2];  s0.w = of[3];
    s1.x = of[4]; s1.y = of[5]; s1.z = of[6];  s1.w = of[7];
    s2.x = of[8]; s2.y = of[9]; s2.z = of[10]; s2.w = of[11];
    out4[(size_t)t * 3 + 0] = s0;
    out4[(size_t)t * 3 + 1] = s1;
    out4[(size_t)t * 3 + 2] = s2;
}

extern "C" void kernel_launch(void* const* d_in, const int* in_sizes, int n_in,
                              void* d_out, int out_size, void* d_ws, size_t ws_size,
                              hipStream_t stream) {
    const float4* x4  = (const float4*)d_in[0];  // [B,3,1]
    const float4* c4  = (const float4*)d_in[1];  // [B,6]
    const float*  psi = (const float*)d_in[2];   // [6,3,3]
    float4* out4 = (float4*)d_out;               // [B,3,1]

    const int B  = in_sizes[1] / 6;  // 2097152, divisible by 4
    const int Tn = B / 4;
    const int block = 256;
    const int grid = (Tn + block - 1) / block;
    expm_kernel<<<grid, block, 0, stream>>>(x4, c4, psi, out4, Tn);
}

// Round 5
// 107.190 us; speedup vs baseline: 1.0328x; 1.0328x over previous
//
#include <hip/hip_runtime.h>

// Batched 3x3 expm(T) @ x, Cayley-Hamilton reduced Taylor (order 10, s=2),
// exp(T)x = E^4 x via 4 matvecs. One batch per thread (round-4 ILP variant
// regressed). NEW: all global traffic is perfectly coalesced float4 via LDS
// staging — round 3 issued 9 scattered VMEM ops/thread (12-24B lane stride);
// this issues ~3 line-aligned dwordx4 ops/thread and services per-thread
// AoS access from LDS (c: 4-way bank alias = 1.58x on 6 reads, x/out: 2-way
// = free per m136).
#define BLOCK 256

__global__ __launch_bounds__(BLOCK) void expm_kernel(
    const float4* __restrict__ x4,
    const float4* __restrict__ c4,
    const float* __restrict__ psi,
    float4* __restrict__ out4)
{
    __shared__ float lds_c[BLOCK * 6];  // 6 KB
    __shared__ float lds_x[BLOCK * 3];  // 3 KB, reused for out staging

    const int tid = threadIdx.x;
    const int cbase = blockIdx.x * (BLOCK * 6 / 4);  // float4 index into c
    const int xbase = blockIdx.x * (BLOCK * 3 / 4);  // float4 index into x/out

    // ---- cooperative coalesced stage: c (384 f4), x (192 f4) ----
    float4* lc4 = reinterpret_cast<float4*>(lds_c);
    float4* lx4 = reinterpret_cast<float4*>(lds_x);
    lc4[tid] = c4[(size_t)cbase + tid];
    if (tid < BLOCK / 2) lc4[BLOCK + tid] = c4[(size_t)cbase + BLOCK + tid];
    if (tid < BLOCK * 3 / 4) lx4[tid] = x4[(size_t)xbase + tid];
    __syncthreads();

    // ---- per-thread inputs from LDS ----
    const float2* cl2 = reinterpret_cast<const float2*>(lds_c + tid * 6);
    const float2 ca = cl2[0], cb = cl2[1], cc = cl2[2];
    const float cm[6] = {ca.x * 0.25f, ca.y * 0.25f,
                         cb.x * 0.25f, cb.y * 0.25f,
                         cc.x * 0.25f, cc.y * 0.25f};
    const float xv0 = lds_x[tid * 3 + 0];
    const float xv1 = lds_x[tid * 3 + 1];
    const float xv2 = lds_x[tid * 3 + 2];

    // ---- A = sum_m (c[m]/4) * psi[m]  (psi uniform -> scalarized) ----
    float A[9];
#pragma unroll
    for (int j = 0; j < 9; ++j) {
        float s = cm[0] * psi[0 * 9 + j];
#pragma unroll
        for (int m = 1; m < 6; ++m) s = fmaf(cm[m], psi[m * 9 + j], s);
        A[j] = s;
    }

    // ---- char-poly: lam^3 = c2v lam^2 + c1v lam + c0v ----
    const float tr  = A[0] + A[4] + A[8];
    const float m01 = fmaf(A[0], A[4], -A[1] * A[3]);
    const float m02 = fmaf(A[0], A[8], -A[2] * A[6]);
    const float m12 = fmaf(A[4], A[8], -A[5] * A[7]);
    const float msum = m01 + m02 + m12;
    const float M10 = fmaf(A[3], A[8], -A[5] * A[6]);
    const float M20 = fmaf(A[3], A[7], -A[4] * A[6]);
    const float det = fmaf(A[0], m12, fmaf(-A[1], M10, A[2] * M20));
    const float c2v = tr, c1v = -msum, c0v = det;

    // ---- reduced Taylor, order 10: exp(A) ~ a0 I + a1 A + a2 A^2 ----
    float p0 = 0.0f, p1 = 0.0f, p2 = 1.0f;
    float a0 = 1.0f, a1 = 1.0f, a2 = 0.5f;
    const float invfact[11] = {0, 0, 0,
        1.6666667e-1f, 4.1666667e-2f, 8.3333333e-3f, 1.3888889e-3f,
        1.9841270e-4f, 2.4801587e-5f, 2.7557319e-6f, 2.7557319e-7f};
#pragma unroll
    for (int k = 3; k <= 10; ++k) {
        const float t0 = c0v * p2;
        const float t1 = fmaf(c1v, p2, p0);
        const float t2 = fmaf(c2v, p2, p1);
        p0 = t0; p1 = t1; p2 = t2;
        const float f = invfact[k];  // constant after unroll
        a0 = fmaf(p0, f, a0);
        a1 = fmaf(p1, f, a1);
        a2 = fmaf(p2, f, a2);
    }

    // ---- E = a0 I + a1 A + a2 A^2 ----
    float E[9];
#pragma unroll
    for (int i = 0; i < 3; ++i) {
#pragma unroll
        for (int j = 0; j < 3; ++j) {
            float v = A[i * 3 + 0] * A[0 * 3 + j];
            v = fmaf(A[i * 3 + 1], A[1 * 3 + j], v);
            v = fmaf(A[i * 3 + 2], A[2 * 3 + j], v);
            E[i * 3 + j] = fmaf(a2, v, a1 * A[i * 3 + j]);
        }
    }
    E[0] += a0; E[4] += a0; E[8] += a0;

    // ---- y = E^4 x  (E = exp(T/4)) ----
    float y0 = xv0, y1 = xv1, y2 = xv2;
#pragma unroll
    for (int r = 0; r < 4; ++r) {
        const float t0 = fmaf(E[0], y0, fmaf(E[1], y1, E[2] * y2));
        const float t1 = fmaf(E[3], y0, fmaf(E[4], y1, E[5] * y2));
        const float t2 = fmaf(E[6], y0, fmaf(E[7], y1, E[8] * y2));
        y0 = t0; y1 = t1; y2 = t2;
    }

    // ---- stage out through LDS (reuse lds_x), coalesced f4 store ----
    __syncthreads();  // all x-reads complete before overwrite
    lds_x[tid * 3 + 0] = y0;
    lds_x[tid * 3 + 1] = y1;
    lds_x[tid * 3 + 2] = y2;
    __syncthreads();
    if (tid < BLOCK * 3 / 4) out4[(size_t)xbase + tid] = lx4[tid];
}

extern "C" void kernel_launch(void* const* d_in, const int* in_sizes, int n_in,
                              void* d_out, int out_size, void* d_ws, size_t ws_size,
                              hipStream_t stream) {
    const float4* x4  = (const float4*)d_in[0];  // [B,3,1]
    const float4* c4  = (const float4*)d_in[1];  // [B,6]
    const float*  psi = (const float*)d_in[2];   // [6,3,3]
    float4* out4 = (float4*)d_out;               // [B,3,1]

    const int B = in_sizes[1] / 6;  // 2097152, divisible by BLOCK
    const int grid = B / BLOCK;
    expm_kernel<<<grid, BLOCK, 0, stream>>>(x4, c4, psi, out4);
}

// Round 6
// 103.404 us; speedup vs baseline: 1.0706x; 1.0366x over previous
//
#include <hip/hip_runtime.h>

// Batched 3x3 expm(T) @ x, T = sum_m c[b,m]*psi[m]. Fully scalar
// Cayley-Hamilton pipeline: exp(A) = b0 I + b1 A + b2 A^2 (A = T/4),
//  (1) order-8 reduced Taylor via 3-term scalar recurrence,
//  (2) TWO squarings done in coefficient space: E^2 = poly-square mod
//      char-poly (15 scalar ops each; never forms the E matrix),
//  (3) tail: y = b0 x + (b1/4) Tx + (b2/16) T(Tx)  (29 ops).
// ~172 core ops/thread vs ~205 in round 3. Kernel is VALU-inst-count
// bound (R1 counters: real inst count ~2x FMA audit), so ops == time.
// R4 (4-batch ILP) and R5 (LDS-coalesced I/O) both regressed: direct
// scattered loads + 1 batch/thread is the best structure found.
__global__ __launch_bounds__(256) void expm_kernel(
    const float* __restrict__ x,
    const float* __restrict__ c,
    const float* __restrict__ psi,
    float* __restrict__ out)
{
    const int b = blockIdx.x * blockDim.x + threadIdx.x;  // B = 2^21 exact

    // ---- c[b,0:6] as 3x float2 (24 B/batch, 8B aligned), unscaled ----
    const float2* c2 = reinterpret_cast<const float2*>(c + (size_t)b * 6);
    const float2 ca = c2[0], cb = c2[1], cc = c2[2];
    const float cm[6] = {ca.x, ca.y, cb.x, cb.y, cc.x, cc.y};

    // ---- T = sum_m c[m] * psi[m]  (psi uniform -> scalarized s_loads) ----
    float T[9];
#pragma unroll
    for (int j = 0; j < 9; ++j) {
        float s = cm[0] * psi[0 * 9 + j];
#pragma unroll
        for (int m = 1; m < 6; ++m) s = fmaf(cm[m], psi[m * 9 + j], s);
        T[j] = s;
    }

    // ---- invariants of T, then scale to A = T/4 ----
    // char poly of A:  lam^3 = c2v lam^2 + c1v lam + c0v
    const float trT  = T[0] + T[4] + T[8];
    const float m01 = fmaf(T[0], T[4], -T[1] * T[3]);
    const float m02 = fmaf(T[0], T[8], -T[2] * T[6]);
    const float m12 = fmaf(T[4], T[8], -T[5] * T[7]);
    const float msT = m01 + m02 + m12;
    const float M10 = fmaf(T[3], T[8], -T[5] * T[6]);
    const float M20 = fmaf(T[3], T[7], -T[4] * T[6]);
    const float detT = fmaf(T[0], m12, fmaf(-T[1], M10, T[2] * M20));
    const float c2v = trT * 0.25f;           // tr(A)
    const float c1v = msT * -0.0625f;        // -msum(A)
    const float c0v = detT * 0.015625f;      // det(A)

    // lam^4 = d2 lam^2 + d1 lam + d0  (fold-back, shared by both squarings)
    const float d2 = fmaf(c2v, c2v, c1v);
    const float d1 = fmaf(c2v, c1v, c0v);
    const float d0 = c2v * c0v;

    // ---- order-8 reduced Taylor: exp(A) ~ b0 I + b1 A + b2 A^2 ----
    float p0 = 0.0f, p1 = 0.0f, p2 = 1.0f;   // A^2 coefficients
    float b0 = 1.0f, b1 = 1.0f, b2 = 0.5f;   // orders 0..2
    const float invfact[9] = {0, 0, 0,
        1.6666667e-1f,   // 1/3!
        4.1666667e-2f,   // 1/4!
        8.3333333e-3f,   // 1/5!
        1.3888889e-3f,   // 1/6!
        1.9841270e-4f,   // 1/7!
        2.4801587e-5f};  // 1/8!
#pragma unroll
    for (int k = 3; k <= 8; ++k) {
        const float t0 = c0v * p2;
        const float t1 = fmaf(c1v, p2, p0);
        const float t2 = fmaf(c2v, p2, p1);
        p0 = t0; p1 = t1; p2 = t2;
        const float f = invfact[k];  // constant after unroll
        b0 = fmaf(p0, f, b0);
        b1 = fmaf(p1, f, b1);
        b2 = fmaf(p2, f, b2);
    }

    // ---- two squarings in coefficient space: (b0,b1,b2) <- (b.^2 mod m) ----
#pragma unroll
    for (int s2 = 0; s2 < 2; ++s2) {
        const float q0 = b0 * b0;
        const float q1 = 2.0f * (b0 * b1);
        const float q2 = fmaf(b1, b1, 2.0f * (b0 * b2));
        const float q3 = 2.0f * (b1 * b2);
        const float q4 = b2 * b2;
        b0 = fmaf(d0, q4, fmaf(c0v, q3, q0));
        b1 = fmaf(d1, q4, fmaf(c1v, q3, q1));
        b2 = fmaf(d2, q4, fmaf(c2v, q3, q2));
    }
    // now exp(T) = b0 I + b1 A + b2 A^2;  A = T/4
    const float b1q = b1 * 0.25f;
    const float b2q = b2 * 0.0625f;

    // ---- y = b0 x + b1q (Tx) + b2q T(Tx) ----
    const float* xb = x + (size_t)b * 3;
    const float x0 = xb[0], x1 = xb[1], x2 = xb[2];
    const float w0 = fmaf(T[0], x0, fmaf(T[1], x1, T[2] * x2));
    const float w1 = fmaf(T[3], x0, fmaf(T[4], x1, T[5] * x2));
    const float w2 = fmaf(T[6], x0, fmaf(T[7], x1, T[8] * x2));
    const float v0 = fmaf(T[0], w0, fmaf(T[1], w1, T[2] * w2));
    const float v1 = fmaf(T[3], w0, fmaf(T[4], w1, T[5] * w2));
    const float v2 = fmaf(T[6], w0, fmaf(T[7], w1, T[8] * w2));

    float* ob = out + (size_t)b * 3;
    ob[0] = fmaf(b0, x0, fmaf(b1q, w0, b2q * v0));
    ob[1] = fmaf(b0, x1, fmaf(b1q, w1, b2q * v1));
    ob[2] = fmaf(b0, x2, fmaf(b1q, w2, b2q * v2));
}

extern "C" void kernel_launch(void* const* d_in, const int* in_sizes, int n_in,
                              void* d_out, int out_size, void* d_ws, size_t ws_size,
                              hipStream_t stream) {
    const float* x   = (const float*)d_in[0];  // [B,3,1]
    const float* c   = (const float*)d_in[1];  // [B,6]
    const float* psi = (const float*)d_in[2];  // [6,3,3]
    float* out = (float*)d_out;                // [B,3,1]

    const int B = in_sizes[1] / 6;  // 2097152 = 2^21, divisible by 256
    const int block = 256;
    const int grid = B / block;
    expm_kernel<<<grid, block, 0, stream>>>(x, c, psi, out);
}